// Round 1
// baseline (5115.630 us; speedup 1.0000x reference)
//
#include <hip/hip_runtime.h>

// ---------------- degree / normalization ----------------

__global__ void k_init_deg(float* __restrict__ deg, int n) {
    int i = blockIdx.x * blockDim.x + threadIdx.x;
    if (i < n) deg[i] = 1.0f;   // self-loop contributes 1
}

__global__ void k_count(const int* __restrict__ dst, float* __restrict__ deg, int e) {
    int i = blockIdx.x * blockDim.x + threadIdx.x;
    if (i < e) atomicAdd(&deg[dst[i]], 1.0f);
}

__global__ void k_rsqrt(float* __restrict__ deg, int n) {
    int i = blockIdx.x * blockDim.x + threadIdx.x;
    if (i < n) deg[i] = rsqrtf(deg[i]);   // deg >= 1 always (self-loop)
}

// ---------------- dense GEMM: C[n x COUT] = A[n x 128] * W[128 x COUT] ----------------

template<int COUT>
__global__ void k_gemm(const float* __restrict__ A, const float* __restrict__ W,
                       float* __restrict__ C, int n) {
    __shared__ float sW[128 * COUT];          // 64KB (COUT=128) / 32KB (COUT=64)
    int tid = threadIdx.x;
    for (int i = tid; i < 128 * COUT; i += blockDim.x) sW[i] = W[i];
    __syncthreads();
    const int ROWS = 256 / COUT;
    int row = blockIdx.x * ROWS + tid / COUT;
    int j = tid % COUT;
    if (row >= n) return;
    const float* a = A + (long)row * 128;
    float acc = 0.f;
#pragma unroll
    for (int k = 0; k < 128; ++k) acc = fmaf(a[k], sW[k * COUT + j], acc);
    C[(long)row * COUT + j] = acc;
}

// ---------------- aggregation ----------------

// out[i][c] = h[i][c] * dinv[i]^2      (self-loop term; pure write, initializes out)
template<int C>
__global__ void k_selfloop(const float* __restrict__ h, const float* __restrict__ dinv,
                           float* __restrict__ out, int n) {
    int t = blockIdx.x * blockDim.x + threadIdx.x;
    int total = n * (C / 4);
    if (t >= total) return;
    int node = t / (C / 4);
    float s = dinv[node]; s *= s;
    float4 v = reinterpret_cast<const float4*>(h)[t];
    float4 o; o.x = v.x * s; o.y = v.y * s; o.z = v.z * s; o.w = v.w * s;
    reinterpret_cast<float4*>(out)[t] = o;
}

// out[dst[e]][c] += h[src[e]][c] * dinv[src]*dinv[dst]
template<int C>
__global__ void k_edge(const int* __restrict__ src, const int* __restrict__ dst,
                       const float* __restrict__ dinv, const float* __restrict__ h,
                       float* __restrict__ out, int e) {
    const int TPE = C / 4;   // threads per edge (float4 each)
    long t = (long)blockIdx.x * blockDim.x + threadIdx.x;
    long idx = t / TPE;
    if (idx >= e) return;
    int c = (int)(t % TPE) * 4;
    int s = src[idx], d = dst[idx];
    float nrm = dinv[s] * dinv[d];
    float4 v = *reinterpret_cast<const float4*>(h + (long)s * C + c);
    float* o = out + (long)d * C + c;
    atomicAdd(o + 0, v.x * nrm);
    atomicAdd(o + 1, v.y * nrm);
    atomicAdd(o + 2, v.z * nrm);
    atomicAdd(o + 3, v.w * nrm);
}

template<int C, bool RELU>
__global__ void k_bias(float* __restrict__ out, const float* __restrict__ b, int n) {
    int t = blockIdx.x * blockDim.x + threadIdx.x;
    int total = n * (C / 4);
    if (t >= total) return;
    int c = (t % (C / 4)) * 4;
    float4 v = reinterpret_cast<float4*>(out)[t];
    v.x += b[c + 0]; v.y += b[c + 1]; v.z += b[c + 2]; v.w += b[c + 3];
    if (RELU) {
        v.x = fmaxf(v.x, 0.f); v.y = fmaxf(v.y, 0.f);
        v.z = fmaxf(v.z, 0.f); v.w = fmaxf(v.w, 0.f);
    }
    reinterpret_cast<float4*>(out)[t] = v;
}

// ---------------- decode: out[k] = dot(z[a[k]], z[b[k]]) over 64 channels ----------------

__global__ void k_decode(const int* __restrict__ ia, const int* __restrict__ ib,
                         const float* __restrict__ z, float* __restrict__ out, int m) {
    int t = blockIdx.x * blockDim.x + threadIdx.x;
    int k = t / 16;            // 16 lanes per label pair
    if (k >= m) return;
    int c = (t & 15) * 4;
    int a = ia[k], b = ib[k];
    float4 va = *reinterpret_cast<const float4*>(z + (long)a * 64 + c);
    float4 vb = *reinterpret_cast<const float4*>(z + (long)b * 64 + c);
    float dot = va.x * vb.x + va.y * vb.y + va.z * vb.z + va.w * vb.w;
    dot += __shfl_xor(dot, 8);
    dot += __shfl_xor(dot, 4);
    dot += __shfl_xor(dot, 2);
    dot += __shfl_xor(dot, 1);
    if ((t & 15) == 0) out[k] = dot;
}

// ---------------- launcher ----------------

extern "C" void kernel_launch(void* const* d_in, const int* in_sizes, int n_in,
                              void* d_out, int out_size, void* d_ws, size_t ws_size,
                              hipStream_t stream) {
    const float* x  = (const float*)d_in[0];
    const int*   ei = (const int*)d_in[1];    // [2, E] row-major: row0=src, row1=dst
    const int*   el = (const int*)d_in[2];    // [2, L]
    const float* W1 = (const float*)d_in[3];
    const float* b1 = (const float*)d_in[4];
    const float* W2 = (const float*)d_in[5];
    const float* b2 = (const float*)d_in[6];
    float* out = (float*)d_out;

    const int N = in_sizes[0] / 128;
    const int E = in_sizes[1] / 2;
    const int L = out_size;

    const int* src = ei;
    const int* dst = ei + E;
    const int* la  = el;
    const int* lb  = el + L;

    float* ws   = (float*)d_ws;
    float* dinv = ws;                       // N
    float* bufA = ws + N;                   // N*128
    float* bufB = bufA + (long)N * 128;     // N*128
    float* z    = bufA;                     // N*64 (reuse)
    float* zout = bufA + (long)N * 64;      // N*64 (reuse)

    auto cdiv = [](long a, long b) { return (int)((a + b - 1) / b); };

    // normalization (shared by both layers)
    k_init_deg<<<cdiv(N, 256), 256, 0, stream>>>(dinv, N);
    k_count   <<<cdiv(E, 256), 256, 0, stream>>>(dst, dinv, E);
    k_rsqrt   <<<cdiv(N, 256), 256, 0, stream>>>(dinv, N);

    // layer 1: h = relu(aggregate(x @ W1) + b1)
    k_gemm<128>    <<<cdiv(N, 2), 256, 0, stream>>>(x, W1, bufA, N);
    k_selfloop<128><<<cdiv((long)N * 32, 256), 256, 0, stream>>>(bufA, dinv, bufB, N);
    k_edge<128>    <<<cdiv((long)E * 32, 256), 256, 0, stream>>>(src, dst, dinv, bufA, bufB, E);
    k_bias<128, true><<<cdiv((long)N * 32, 256), 256, 0, stream>>>(bufB, b1, N);

    // layer 2: z = aggregate(h @ W2) + b2
    k_gemm<64>     <<<cdiv(N, 4), 256, 0, stream>>>(bufB, W2, z, N);
    k_selfloop<64> <<<cdiv((long)N * 16, 256), 256, 0, stream>>>(z, dinv, zout, N);
    k_edge<64>     <<<cdiv((long)E * 16, 256), 256, 0, stream>>>(src, dst, dinv, z, zout, E);
    k_bias<64, false><<<cdiv((long)N * 16, 256), 256, 0, stream>>>(zout, b2, N);

    // decode
    k_decode<<<cdiv((long)L * 16, 256), 256, 0, stream>>>(la, lb, zout, out, L);
}

// Round 2
// 3969.948 us; speedup vs baseline: 1.2886x; 1.2886x over previous
//
#include <hip/hip_runtime.h>

// ================= degree / normalization =================

__global__ void k_count(const int* __restrict__ dst, int* __restrict__ cnt, int e) {
    int i = blockIdx.x * blockDim.x + threadIdx.x;
    if (i < e) atomicAdd(&cnt[dst[i]], 1);
}

__global__ void k_dinv(const int* __restrict__ cnt, float* __restrict__ dinv, int n) {
    int i = blockIdx.x * blockDim.x + threadIdx.x;
    if (i < n) dinv[i] = rsqrtf((float)(cnt[i] + 1));   // +1 self-loop
}

// Single-block exclusive scan over cnt -> rowptr (and cursor copy).
__global__ void k_scan(const int* __restrict__ cnt, int* __restrict__ rowptr,
                       int* __restrict__ cursor, int n) {
    __shared__ int part[1024];
    int tid = threadIdx.x;
    int chunk = (n + 1023) >> 10;
    int beg = tid * chunk;
    int end = min(beg + chunk, n);
    int s = 0;
    for (int i = beg; i < end; ++i) s += cnt[i];
    part[tid] = s;
    __syncthreads();
    for (int off = 1; off < 1024; off <<= 1) {
        int v = (tid >= off) ? part[tid - off] : 0;
        __syncthreads();
        part[tid] += v;
        __syncthreads();
    }
    int run = (tid == 0) ? 0 : part[tid - 1];
    for (int i = beg; i < end; ++i) {
        rowptr[i] = run;
        cursor[i] = run;
        run += cnt[i];
    }
    if (tid == 0) rowptr[n] = part[1023];
}

__global__ void k_fill(const int* __restrict__ src, const int* __restrict__ dstv,
                       int* __restrict__ cursor, int* __restrict__ csr_src, int e) {
    int i = blockIdx.x * blockDim.x + threadIdx.x;
    if (i < e) {
        int d = dstv[i];
        int pos = atomicAdd(&cursor[d], 1);
        csr_src[pos] = src[i];
    }
}

// ================= GEMM: C[n x COUT] = A[n x 128] * W[128 x COUT] =================
// 256 threads/block. Each thread: RPT rows x 4 cols. W staged in LDS.

template<int COUT, int RPT>
__global__ void k_gemm(const float* __restrict__ A, const float* __restrict__ W,
                       float* __restrict__ C, int n) {
    __shared__ float sW[128 * COUT];
    int tid = threadIdx.x;
    float4* sW4 = reinterpret_cast<float4*>(sW);
    const float4* W4 = reinterpret_cast<const float4*>(W);
    for (int i = tid; i < 128 * COUT / 4; i += 256) sW4[i] = W4[i];
    __syncthreads();

    const int JG = COUT / 4;        // column-groups (threads per row-group)
    const int TR = 256 / JG;        // row-groups per block
    const int ROWS = TR * RPT;      // rows per block
    int rg = tid / JG;
    int j  = (tid % JG) * 4;
    int row0 = blockIdx.x * ROWS + rg * RPT;

    const float4* A4 = reinterpret_cast<const float4*>(A);
    float4 acc[RPT];
#pragma unroll
    for (int r = 0; r < RPT; ++r) acc[r] = make_float4(0.f, 0.f, 0.f, 0.f);

#pragma unroll
    for (int k4 = 0; k4 < 32; ++k4) {
        float4 a[RPT];
#pragma unroll
        for (int r = 0; r < RPT; ++r) {
            int rr = min(row0 + r, n - 1);
            a[r] = A4[(long)rr * 32 + k4];
        }
#pragma unroll
        for (int kk = 0; kk < 4; ++kk) {
            float4 w = sW4[((k4 * 4 + kk) * COUT + j) >> 2];
#pragma unroll
            for (int r = 0; r < RPT; ++r) {
                float av = (kk == 0) ? a[r].x : (kk == 1) ? a[r].y : (kk == 2) ? a[r].z : a[r].w;
                acc[r].x = fmaf(av, w.x, acc[r].x);
                acc[r].y = fmaf(av, w.y, acc[r].y);
                acc[r].z = fmaf(av, w.z, acc[r].z);
                acc[r].w = fmaf(av, w.w, acc[r].w);
            }
        }
    }
    float4* C4 = reinterpret_cast<float4*>(C);
#pragma unroll
    for (int r = 0; r < RPT; ++r) {
        int row = row0 + r;
        if (row < n) C4[((long)row * COUT + j) >> 2] = acc[r];
    }
}

// ================= pull aggregation (self-loop + gather + bias [+ relu]) =================

template<int C, bool RELU>
__global__ void k_gather(const int* __restrict__ rowptr, const int* __restrict__ csr_src,
                         const float* __restrict__ dinv, const float* __restrict__ h,
                         const float* __restrict__ bias, float* __restrict__ out, int n) {
    const int TPN = C / 4;          // threads per node
    int t = blockIdx.x * blockDim.x + threadIdx.x;
    int node = t / TPN;
    if (node >= n) return;
    int c = (t % TPN) * 4;

    const float4* h4 = reinterpret_cast<const float4*>(h);
    float dd = dinv[node];
    float sl = dd * dd;
    float4 v = h4[((long)node * C + c) >> 2];
    float4 acc;
    acc.x = v.x * sl; acc.y = v.y * sl; acc.z = v.z * sl; acc.w = v.w * sl;

    int beg = rowptr[node], end = rowptr[node + 1];
    for (int e = beg; e < end; ++e) {
        int s = csr_src[e];
        float nrm = dinv[s] * dd;
        float4 u = h4[((long)s * C + c) >> 2];
        acc.x = fmaf(u.x, nrm, acc.x);
        acc.y = fmaf(u.y, nrm, acc.y);
        acc.z = fmaf(u.z, nrm, acc.z);
        acc.w = fmaf(u.w, nrm, acc.w);
    }
    float4 b4 = *reinterpret_cast<const float4*>(bias + c);
    acc.x += b4.x; acc.y += b4.y; acc.z += b4.z; acc.w += b4.w;
    if (RELU) {
        acc.x = fmaxf(acc.x, 0.f); acc.y = fmaxf(acc.y, 0.f);
        acc.z = fmaxf(acc.z, 0.f); acc.w = fmaxf(acc.w, 0.f);
    }
    reinterpret_cast<float4*>(out)[((long)node * C + c) >> 2] = acc;
}

// ================= decode =================

__global__ void k_decode(const int* __restrict__ ia, const int* __restrict__ ib,
                         const float* __restrict__ z, float* __restrict__ out, int m) {
    int t = blockIdx.x * blockDim.x + threadIdx.x;
    int k = t / 16;
    if (k >= m) return;
    int c = (t & 15) * 4;
    int a = ia[k], b = ib[k];
    float4 va = *reinterpret_cast<const float4*>(z + (long)a * 64 + c);
    float4 vb = *reinterpret_cast<const float4*>(z + (long)b * 64 + c);
    float dot = va.x * vb.x + va.y * vb.y + va.z * vb.z + va.w * vb.w;
    dot += __shfl_xor(dot, 8);
    dot += __shfl_xor(dot, 4);
    dot += __shfl_xor(dot, 2);
    dot += __shfl_xor(dot, 1);
    if ((t & 15) == 0) out[k] = dot;
}

// ================= launcher =================

extern "C" void kernel_launch(void* const* d_in, const int* in_sizes, int n_in,
                              void* d_out, int out_size, void* d_ws, size_t ws_size,
                              hipStream_t stream) {
    const float* x  = (const float*)d_in[0];
    const int*   ei = (const int*)d_in[1];
    const int*   el = (const int*)d_in[2];
    const float* W1 = (const float*)d_in[3];
    const float* b1 = (const float*)d_in[4];
    const float* W2 = (const float*)d_in[5];
    const float* b2 = (const float*)d_in[6];
    float* out = (float*)d_out;

    const int N = in_sizes[0] / 128;
    const int E = in_sizes[1] / 2;
    const int L = out_size;

    const int* src = ei;
    const int* dst = ei + E;
    const int* la  = el;
    const int* lb  = el + L;

    // ---- workspace layout (16B-aligned big buffers first) ----
    float* bufA = (float*)d_ws;                 // N*128
    float* bufB = bufA + (long)N * 128;         // N*128
    int*   cnt  = (int*)(bufB + (long)N * 128); // N
    int*   rowptr = cnt + N;                    // N+1
    int*   cursor = rowptr + N + 1;             // N
    float* dinv   = (float*)(cursor + N);       // N
    int*   csr_src = (int*)(dinv + N);          // E
    float* z    = bufA;                         // N*64 (reuse)
    float* zout = bufA + (long)N * 64;          // N*64 (reuse)

    auto cdiv = [](long a, long b) { return (int)((a + b - 1) / b); };

    // ---- CSR build + normalization ----
    hipMemsetAsync(cnt, 0, (size_t)N * sizeof(int), stream);
    k_count<<<cdiv(E, 256), 256, 0, stream>>>(dst, cnt, E);
    k_dinv <<<cdiv(N, 256), 256, 0, stream>>>(cnt, dinv, N);
    k_scan <<<1, 1024, 0, stream>>>(cnt, rowptr, cursor, N);
    k_fill <<<cdiv(E, 256), 256, 0, stream>>>(src, dst, cursor, csr_src, E);

    // ---- layer 1: h = relu(agg(x @ W1) + b1) ----
    k_gemm<128, 4><<<cdiv(N, 32), 256, 0, stream>>>(x, W1, bufA, N);
    k_gather<128, true><<<cdiv((long)N * 32, 256), 256, 0, stream>>>(
        rowptr, csr_src, dinv, bufA, b1, bufB, N);

    // ---- layer 2: z = agg(h @ W2) + b2 ----
    k_gemm<64, 4><<<cdiv(N, 64), 256, 0, stream>>>(bufB, W2, z, N);
    k_gather<64, false><<<cdiv((long)N * 16, 256), 256, 0, stream>>>(
        rowptr, csr_src, dinv, z, b2, zout, N);

    // ---- decode ----
    k_decode<<<cdiv((long)L * 16, 256), 256, 0, stream>>>(la, lb, zout, out, L);
}

// Round 3
// 542.066 us; speedup vs baseline: 9.4373x; 7.3237x over previous
//
#include <hip/hip_runtime.h>

// ================= degree / normalization =================

__global__ void k_count(const int* __restrict__ dst, int* __restrict__ cnt, int e) {
    int i = blockIdx.x * blockDim.x + threadIdx.x;
    if (i < e) atomicAdd(&cnt[dst[i]], 1);
}

__global__ void k_dinv(const int* __restrict__ cnt, float* __restrict__ dinv, int n) {
    int i = blockIdx.x * blockDim.x + threadIdx.x;
    if (i < n) dinv[i] = rsqrtf((float)(cnt[i] + 1));   // +1 self-loop
}

// ---- 3-phase scan over cnt -> rowptr/cursor ----
#define SCP 1024

__global__ void k_scan_a(const int* __restrict__ cnt, int* __restrict__ part, int n) {
    int p = blockIdx.x * blockDim.x + threadIdx.x;
    if (p >= SCP) return;
    int chunk = (n + SCP - 1) / SCP;
    int b = p * chunk, e = min(b + chunk, n), s = 0;
    for (int i = b; i < e; ++i) s += cnt[i];
    part[p] = s;
}

__global__ void k_scan_b(int* __restrict__ part) {   // 1 block, 1024 threads
    __shared__ int sm[SCP];
    int t = threadIdx.x;
    sm[t] = part[t];
    __syncthreads();
    for (int off = 1; off < SCP; off <<= 1) {
        int v = (t >= off) ? sm[t - off] : 0;
        __syncthreads();
        sm[t] += v;
        __syncthreads();
    }
    part[t] = t ? sm[t - 1] : 0;   // exclusive
}

__global__ void k_scan_c(const int* __restrict__ cnt, const int* __restrict__ part,
                         int* __restrict__ rowptr, int* __restrict__ cursor, int n) {
    int p = blockIdx.x * blockDim.x + threadIdx.x;
    if (p >= SCP) return;
    int chunk = (n + SCP - 1) / SCP;
    int b = p * chunk, e = min(b + chunk, n);
    int run = part[p];
    for (int i = b; i < e; ++i) { rowptr[i] = run; cursor[i] = run; run += cnt[i]; }
    if (p == SCP - 1) rowptr[n] = run;
}

__global__ void k_fill(const int* __restrict__ src, const int* __restrict__ dstv,
                       const float* __restrict__ dinv, int* __restrict__ cursor,
                       int* __restrict__ csr_src, float* __restrict__ csr_nrm, int e) {
    int i = blockIdx.x * blockDim.x + threadIdx.x;
    if (i < e) {
        int d = dstv[i], s = src[i];
        int pos = atomicAdd(&cursor[d], 1);
        csr_src[pos] = s;
        csr_nrm[pos] = dinv[s] * dinv[d];
    }
}

// ================= GEMM: C[n x COUT] = A[n x 128] * W[128 x COUT] =================
// Classic LDS-tiled register-blocked fp32 GEMM. BM=128 rows/block, BK=32 k-slab.
// 256 threads as 16x16; thread tile = 8 rows x TN cols (TN = COUT/16).

template<int COUT>
__global__ __launch_bounds__(256) void k_gemm(const float* __restrict__ A,
                                              const float* __restrict__ W,
                                              float* __restrict__ C, int n) {
    const int BM = 128, BK = 32;
    const int TN = COUT / 16;                 // 8 (COUT=128) or 4 (COUT=64)
    __shared__ float sA[BK][BM + 4];          // [k][row], stride 132 floats (528B, 16B-aligned)
    __shared__ float sW[BK][COUT + 4];        // [k][col], stride 132/68 (16B-aligned)

    int tid = threadIdx.x;
    int row0 = blockIdx.x * BM;
    int tr = tid & 15, tc = tid >> 4;
    int r0 = tr * 8, c0 = tc * TN;

    float acc[8][TN];
#pragma unroll
    for (int i = 0; i < 8; ++i)
#pragma unroll
        for (int j = 0; j < TN; ++j) acc[i][j] = 0.f;

    for (int slab = 0; slab < 4; ++slab) {
        // ---- stage A slab (128 rows x 32 k), transposed into sA[k][row] ----
#pragma unroll
        for (int t = 0; t < 4; ++t) {
            int f = tid + t * 256;            // 1024 float4s
            int row = f >> 3, k4 = f & 7;     // 8 float4 per row-slab
            int gr = min(row0 + row, n - 1);
            float4 v = *reinterpret_cast<const float4*>(A + (long)gr * 128 + slab * 32 + k4 * 4);
            sA[k4 * 4 + 0][row] = v.x;
            sA[k4 * 4 + 1][row] = v.y;
            sA[k4 * 4 + 2][row] = v.z;
            sA[k4 * 4 + 3][row] = v.w;
        }
        // ---- stage W slab (32 k x COUT) ----
        const int WF4 = BK * COUT / 4;
        for (int f = tid; f < WF4; f += 256) {
            int k = f / (COUT / 4), c4 = (f % (COUT / 4)) * 4;
            float4 v = *reinterpret_cast<const float4*>(W + (long)(slab * 32 + k) * COUT + c4);
            *reinterpret_cast<float4*>(&sW[k][c4]) = v;
        }
        __syncthreads();

#pragma unroll
        for (int k = 0; k < BK; ++k) {
            float a[8], w[TN];
            *reinterpret_cast<float4*>(&a[0]) = *reinterpret_cast<const float4*>(&sA[k][r0]);
            *reinterpret_cast<float4*>(&a[4]) = *reinterpret_cast<const float4*>(&sA[k][r0 + 4]);
#pragma unroll
            for (int j = 0; j < TN; j += 4)
                *reinterpret_cast<float4*>(&w[j]) = *reinterpret_cast<const float4*>(&sW[k][c0 + j]);
#pragma unroll
            for (int i = 0; i < 8; ++i)
#pragma unroll
                for (int j = 0; j < TN; ++j)
                    acc[i][j] = fmaf(a[i], w[j], acc[i][j]);
        }
        __syncthreads();
    }

    // ---- write C ----
#pragma unroll
    for (int i = 0; i < 8; ++i) {
        int row = row0 + r0 + i;
        if (row < n) {
#pragma unroll
            for (int j = 0; j < TN; j += 4)
                *reinterpret_cast<float4*>(C + (long)row * COUT + c0 + j) =
                    *reinterpret_cast<float4*>(&acc[i][j]);
        }
    }
}

// ================= pull aggregation (self-loop + gather + bias [+ relu]) =================

template<int C, bool RELU>
__global__ void k_gather(const int* __restrict__ rowptr, const int* __restrict__ csr_src,
                         const float* __restrict__ csr_nrm, const float* __restrict__ dinv,
                         const float* __restrict__ h, const float* __restrict__ bias,
                         float* __restrict__ out, int n) {
    const int TPN = C / 4;
    int t = blockIdx.x * blockDim.x + threadIdx.x;
    int node = t / TPN;
    if (node >= n) return;
    int c = (t % TPN) * 4;

    const float4* h4 = reinterpret_cast<const float4*>(h);
    float dd = dinv[node];
    float sl = dd * dd;
    float4 v = h4[((long)node * C + c) >> 2];
    float4 acc;
    acc.x = v.x * sl; acc.y = v.y * sl; acc.z = v.z * sl; acc.w = v.w * sl;

    int beg = rowptr[node], end = rowptr[node + 1];
    int e = beg;
    for (; e + 4 <= end; e += 4) {
        int s0 = csr_src[e + 0], s1 = csr_src[e + 1];
        int s2 = csr_src[e + 2], s3 = csr_src[e + 3];
        float n0 = csr_nrm[e + 0], n1 = csr_nrm[e + 1];
        float n2 = csr_nrm[e + 2], n3 = csr_nrm[e + 3];
        float4 u0 = h4[((long)s0 * C + c) >> 2];
        float4 u1 = h4[((long)s1 * C + c) >> 2];
        float4 u2 = h4[((long)s2 * C + c) >> 2];
        float4 u3 = h4[((long)s3 * C + c) >> 2];
        acc.x = fmaf(u0.x, n0, fmaf(u1.x, n1, fmaf(u2.x, n2, fmaf(u3.x, n3, acc.x))));
        acc.y = fmaf(u0.y, n0, fmaf(u1.y, n1, fmaf(u2.y, n2, fmaf(u3.y, n3, acc.y))));
        acc.z = fmaf(u0.z, n0, fmaf(u1.z, n1, fmaf(u2.z, n2, fmaf(u3.z, n3, acc.z))));
        acc.w = fmaf(u0.w, n0, fmaf(u1.w, n1, fmaf(u2.w, n2, fmaf(u3.w, n3, acc.w))));
    }
    for (; e < end; ++e) {
        int s = csr_src[e];
        float nr = csr_nrm[e];
        float4 u = h4[((long)s * C + c) >> 2];
        acc.x = fmaf(u.x, nr, acc.x);
        acc.y = fmaf(u.y, nr, acc.y);
        acc.z = fmaf(u.z, nr, acc.z);
        acc.w = fmaf(u.w, nr, acc.w);
    }
    float4 b4 = *reinterpret_cast<const float4*>(bias + c);
    acc.x += b4.x; acc.y += b4.y; acc.z += b4.z; acc.w += b4.w;
    if (RELU) {
        acc.x = fmaxf(acc.x, 0.f); acc.y = fmaxf(acc.y, 0.f);
        acc.z = fmaxf(acc.z, 0.f); acc.w = fmaxf(acc.w, 0.f);
    }
    reinterpret_cast<float4*>(out)[((long)node * C + c) >> 2] = acc;
}

// ================= decode =================

__global__ void k_decode(const int* __restrict__ ia, const int* __restrict__ ib,
                         const float* __restrict__ z, float* __restrict__ out, int m) {
    int t = blockIdx.x * blockDim.x + threadIdx.x;
    int k = t / 16;
    if (k >= m) return;
    int c = (t & 15) * 4;
    int a = ia[k], b = ib[k];
    float4 va = *reinterpret_cast<const float4*>(z + (long)a * 64 + c);
    float4 vb = *reinterpret_cast<const float4*>(z + (long)b * 64 + c);
    float dot = va.x * vb.x + va.y * vb.y + va.z * vb.z + va.w * vb.w;
    dot += __shfl_xor(dot, 8);
    dot += __shfl_xor(dot, 4);
    dot += __shfl_xor(dot, 2);
    dot += __shfl_xor(dot, 1);
    if ((t & 15) == 0) out[k] = dot;
}

// ================= launcher =================

extern "C" void kernel_launch(void* const* d_in, const int* in_sizes, int n_in,
                              void* d_out, int out_size, void* d_ws, size_t ws_size,
                              hipStream_t stream) {
    const float* x  = (const float*)d_in[0];
    const int*   ei = (const int*)d_in[1];
    const int*   el = (const int*)d_in[2];
    const float* W1 = (const float*)d_in[3];
    const float* b1 = (const float*)d_in[4];
    const float* W2 = (const float*)d_in[5];
    const float* b2 = (const float*)d_in[6];
    float* out = (float*)d_out;

    const int N = in_sizes[0] / 128;
    const int E = in_sizes[1] / 2;
    const int L = out_size;

    const int* src = ei;
    const int* dst = ei + E;
    const int* la  = el;
    const int* lb  = el + L;

    // ---- workspace layout (16B-aligned big buffers first) ----
    float* bufA = (float*)d_ws;                     // N*128
    float* bufB = bufA + (long)N * 128;             // N*128
    float* csr_nrm = bufB + (long)N * 128;          // E
    int*   csr_src = (int*)(csr_nrm + E);           // E
    int*   cnt     = csr_src + E;                   // N
    int*   rowptr  = cnt + N;                       // N+1
    int*   cursor  = rowptr + N + 1;                // N
    float* dinv    = (float*)(cursor + N);          // N
    int*   part    = (int*)(dinv + N);              // SCP
    float* z    = bufA;                             // N*64 (reuse)
    float* zout = bufA + (long)N * 64;              // N*64 (reuse)

    auto cdiv = [](long a, long b) { return (int)((a + b - 1) / b); };

    // ---- CSR build + normalization ----
    hipMemsetAsync(cnt, 0, (size_t)N * sizeof(int), stream);
    k_count <<<cdiv(E, 256), 256, 0, stream>>>(dst, cnt, E);
    k_dinv  <<<cdiv(N, 256), 256, 0, stream>>>(cnt, dinv, N);
    k_scan_a<<<SCP / 256, 256, 0, stream>>>(cnt, part, N);
    k_scan_b<<<1, SCP, 0, stream>>>(part);
    k_scan_c<<<SCP / 256, 256, 0, stream>>>(cnt, part, rowptr, cursor, N);
    k_fill  <<<cdiv(E, 256), 256, 0, stream>>>(src, dst, dinv, cursor, csr_src, csr_nrm, E);

    // ---- layer 1: h = relu(agg(x @ W1) + b1) ----
    k_gemm<128><<<cdiv(N, 128), 256, 0, stream>>>(x, W1, bufA, N);
    k_gather<128, true><<<cdiv((long)N * 32, 256), 256, 0, stream>>>(
        rowptr, csr_src, csr_nrm, dinv, bufA, b1, bufB, N);

    // ---- layer 2: z = agg(h @ W2) + b2 ----
    k_gemm<64><<<cdiv(N, 128), 256, 0, stream>>>(bufB, W2, z, N);
    k_gather<64, false><<<cdiv((long)N * 16, 256), 256, 0, stream>>>(
        rowptr, csr_src, csr_nrm, dinv, z, b2, zout, N);

    // ---- decode ----
    k_decode<<<cdiv((long)L * 16, 256), 256, 0, stream>>>(la, lb, zout, out, L);
}